// Round 2
// baseline (287.725 us; speedup 1.0000x reference)
//
#include <hip/hip_runtime.h>
#include <hip/hip_bf16.h>

// One block per image (8192 = N*B images), 256 threads.
// Computes full CNN -> softmax -> digit probs + guard probs. All fp32.
__global__ __launch_bounds__(256) void cnn_kernel(
    const float* __restrict__ seq,
    const float* __restrict__ w1g, const float* __restrict__ b1g,
    const float* __restrict__ w2g, const float* __restrict__ b2g,
    const float* __restrict__ w3g, const float* __restrict__ b3g,
    const float* __restrict__ wdg, const float* __restrict__ bdg,
    float* __restrict__ out, float* __restrict__ g_ws)
{
    __shared__ __align__(16) float s_img[28 * 28];
    __shared__ float s_p1[8][13][13];   // pool(relu(conv1))
    __shared__ float s_p2[16][5][5];    // pool(relu(conv2))
    __shared__ float s_c3[32][4];       // relu(conv3) at the 2x2 pooled window
    __shared__ float s_p3[32];          // pooled conv3 (the 32-dim feature)
    __shared__ float s_logit[10];
    __shared__ float s_prob[10];
    __shared__ __align__(16) float s_w1[8][9];
    __shared__ float s_b1[8];
    __shared__ __align__(16) float s_w2[16][8][9];
    __shared__ float s_b2[16];
    __shared__ __align__(16) float s_w3[32][16][9];
    __shared__ float s_b3[32];
    __shared__ __align__(16) float s_wd[10][32];
    __shared__ float s_bd[10];

    const int tid = threadIdx.x;
    const int m   = blockIdx.x;        // image id = n*256 + b, n = t*4 + d
    const int n   = m >> 8;
    const int b   = m & 255;
    const int t   = n >> 2;
    const int d   = n & 3;

    // sequences: (B=256, T=8, D=4, 1, 28, 28); 784 floats = 196 float4 (16B aligned)
    const float4* src4 = (const float4*)(seq + (((size_t)b * 8 + t) * 4 + d) * 784);
    float4* s_img4 = (float4*)s_img;
    if (tid < 196) s_img4[tid] = src4[tid];

    // weights (all counts divisible by 4, buffers 16B aligned)
    {
        const float4* w1_4 = (const float4*)w1g;   // 18
        const float4* w2_4 = (const float4*)w2g;   // 288
        const float4* w3_4 = (const float4*)w3g;   // 1152
        const float4* wd_4 = (const float4*)wdg;   // 80
        float4* d1 = (float4*)&s_w1[0][0];
        float4* d2 = (float4*)&s_w2[0][0][0];
        float4* d3 = (float4*)&s_w3[0][0][0];
        float4* dd = (float4*)&s_wd[0][0];
        for (int i = tid; i < 18;   i += 256) d1[i] = w1_4[i];
        for (int i = tid; i < 288;  i += 256) d2[i] = w2_4[i];
        for (int i = tid; i < 1152; i += 256) d3[i] = w3_4[i];
        for (int i = tid; i < 80;   i += 256) dd[i] = wd_4[i];
        if (tid < 8)  s_b1[tid] = b1g[tid];
        if (tid < 16) s_b2[tid] = b2g[tid];
        if (tid < 32) s_b3[tid] = b3g[tid];
        if (tid < 10) s_bd[tid] = bdg[tid];
    }
    __syncthreads();

    // ---- stage 1: conv1(1->8, 3x3 VALID 28->26) + relu + pool2 -> (8,13,13)
    for (int idx = tid; idx < 8 * 169; idx += 256) {
        int c   = idx / 169;
        int rem = idx - c * 169;
        int y   = rem / 13;
        int x   = rem - y * 13;
        int r0 = 2 * y, c0 = 2 * x;
        float p[4][4];
        #pragma unroll
        for (int i = 0; i < 4; i++)
            #pragma unroll
            for (int j = 0; j < 4; j++)
                p[i][j] = s_img[(r0 + i) * 28 + (c0 + j)];
        const float* W = s_w1[c];
        const float bias = s_b1[c];
        float acc = 0.f;
        #pragma unroll
        for (int dy = 0; dy < 2; dy++)
            #pragma unroll
            for (int dx = 0; dx < 2; dx++) {
                float v = bias;
                #pragma unroll
                for (int i = 0; i < 3; i++)
                    #pragma unroll
                    for (int j = 0; j < 3; j++)
                        v += p[dy + i][dx + j] * W[i * 3 + j];
                acc += fmaxf(v, 0.f);
            }
        s_p1[c][y][x] = 0.25f * acc;
    }
    __syncthreads();

    // ---- stage 2: conv2(8->16, 13->11) + relu + pool2 (floor: 11->5) -> (16,5,5)
    for (int idx = tid; idx < 16 * 25; idx += 256) {
        int c   = idx / 25;
        int rem = idx - c * 25;
        int y   = rem / 5;
        int x   = rem - y * 5;
        int r0 = 2 * y, c0 = 2 * x;
        const float bias = s_b2[c];
        float v00 = bias, v01 = bias, v10 = bias, v11 = bias;
        for (int ic = 0; ic < 8; ic++) {
            float p[4][4];
            #pragma unroll
            for (int i = 0; i < 4; i++)
                #pragma unroll
                for (int j = 0; j < 4; j++)
                    p[i][j] = s_p1[ic][r0 + i][c0 + j];
            const float* W = s_w2[c][ic];
            float w[9];
            #pragma unroll
            for (int k = 0; k < 9; k++) w[k] = W[k];
            #pragma unroll
            for (int i = 0; i < 3; i++)
                #pragma unroll
                for (int j = 0; j < 3; j++) {
                    float wk = w[i * 3 + j];
                    v00 += p[i    ][j    ] * wk;
                    v01 += p[i    ][j + 1] * wk;
                    v10 += p[i + 1][j    ] * wk;
                    v11 += p[i + 1][j + 1] * wk;
                }
        }
        s_p2[c][y][x] = 0.25f * (fmaxf(v00, 0.f) + fmaxf(v01, 0.f) +
                                 fmaxf(v10, 0.f) + fmaxf(v11, 0.f));
    }
    __syncthreads();

    // ---- stage 3: conv3(16->32, 5->3) + relu; pool(2,2) floor only uses 2x2 window
    if (tid < 128) {
        int c = tid >> 2;
        int u = (tid >> 1) & 1;
        int v = tid & 1;
        float acc = s_b3[c];
        for (int ic = 0; ic < 16; ic++) {
            const float* W = s_w3[c][ic];
            #pragma unroll
            for (int i = 0; i < 3; i++)
                #pragma unroll
                for (int j = 0; j < 3; j++)
                    acc += s_p2[ic][u + i][v + j] * W[i * 3 + j];
        }
        s_c3[c][(u << 1) | v] = fmaxf(acc, 0.f);
    }
    __syncthreads();
    if (tid < 32)
        s_p3[tid] = 0.25f * (s_c3[tid][0] + s_c3[tid][1] + s_c3[tid][2] + s_c3[tid][3]);
    __syncthreads();

    // ---- dense + softmax
    if (tid < 10) {
        float acc = s_bd[tid];
        #pragma unroll
        for (int c2 = 0; c2 < 32; c2++) acc += s_p3[c2] * s_wd[tid][c2];
        s_logit[tid] = acc;
    }
    __syncthreads();
    if (tid < 10) {
        float mx = s_logit[0];
        #pragma unroll
        for (int k = 1; k < 10; k++) mx = fmaxf(mx, s_logit[k]);
        float ssum = 0.f;
        #pragma unroll
        for (int k = 0; k < 10; k++) ssum += __expf(s_logit[k] - mx);
        float p = __expf(s_logit[tid] - mx) / ssum;
        s_prob[tid] = p;
        out[(size_t)m * 10 + tid] = p;                 // all_cnn_preds (N,B,10)
    }
    __syncthreads();
    if (tid < 6) {
        // rules: [p8, p4+p6, p0+p2, p7+p9, p5, p1+p3]; nibble-packed index tables
        int ia = (0x157048 >> (tid * 4)) & 0xF;
        int ib = (0x3F926F >> (tid * 4)) & 0xF;
        float gv = s_prob[ia] + (ib < 10 ? s_prob[ib] : 0.f);
        out[81920 + (size_t)m * 6 + tid] = gv;         // all_guard_preds (N,B,6)
        g_ws[(size_t)m * 6 + tid] = gv;                // scratch for recurrence
    }
}

// 4 blocks x 64 threads; thread = one batch element. M (6x10x10) in LDS, broadcast reads.
__global__ __launch_bounds__(64) void sfa_kernel(
    const float* __restrict__ trans,
    const float* __restrict__ g_ws,
    float* __restrict__ out)
{
    __shared__ float M[6][10][10];
    const int tid = threadIdx.x;

    if (tid < 54) {
        int r = tid / 9, i = tid - r * 9;
        const float* row = trans + (size_t)(r * 9 + i) * 10;
        float x[10], mx = -1e30f;
        #pragma unroll
        for (int j = 0; j < 10; j++) { x[j] = 10.f * row[j]; mx = fmaxf(mx, x[j]); }
        float s = 0.f;
        #pragma unroll
        for (int j = 0; j < 10; j++) { x[j] = __expf(x[j] - mx); s += x[j]; }
        float inv = 1.f / s;
        #pragma unroll
        for (int j = 0; j < 10; j++) M[r][i][j] = x[j] * inv;
    } else if (tid < 60) {
        int r = tid - 54;
        #pragma unroll
        for (int j = 0; j < 10; j++) M[r][9][j] = (j == 9) ? 1.f : 0.f;
    }
    __syncthreads();

    const int b = blockIdx.x * 64 + tid;
    float st[10];
    st[0] = 1.f;
    #pragma unroll
    for (int j = 1; j < 10; j++) st[j] = 0.f;

    for (int n = 0; n < 32; n++) {
        const float* gp = g_ws + ((size_t)n * 256 + b) * 6;
        float g[6];
        #pragma unroll
        for (int r = 0; r < 6; r++) g[r] = gp[r];

        float ns[10];
        #pragma unroll
        for (int j = 0; j < 10; j++) ns[j] = 0.f;
        ns[9] = st[9];                                  // accepting row: sum_r g_r = 1
        #pragma unroll
        for (int r = 0; r < 6; r++) {
            float gr = g[r];
            #pragma unroll
            for (int i = 0; i < 9; i++) {
                float c = gr * st[i];
                #pragma unroll
                for (int j = 0; j < 10; j++)
                    ns[j] += c * M[r][i][j];
            }
        }
        #pragma unroll
        for (int j = 0; j < 10; j++) st[j] = ns[j];
    }

    #pragma unroll
    for (int j = 0; j < 10; j++)
        out[131072 + (size_t)b * 10 + j] = st[j];       // state_final (B,10)
}

extern "C" void kernel_launch(void* const* d_in, const int* in_sizes, int n_in,
                              void* d_out, int out_size, void* d_ws, size_t ws_size,
                              hipStream_t stream) {
    const float* seq = (const float*)d_in[0];
    const float* w1  = (const float*)d_in[1];
    const float* b1  = (const float*)d_in[2];
    const float* w2  = (const float*)d_in[3];
    const float* b2  = (const float*)d_in[4];
    const float* w3  = (const float*)d_in[5];
    const float* b3  = (const float*)d_in[6];
    const float* wd  = (const float*)d_in[7];
    const float* bd  = (const float*)d_in[8];
    const float* tr  = (const float*)d_in[9];
    float* out  = (float*)d_out;
    float* g_ws = (float*)d_ws;   // 8192*6 fp32 = 196608 B guard scratch

    cnn_kernel<<<8192, 256, 0, stream>>>(seq, w1, b1, w2, b2, w3, b3, wd, bd, out, g_ws);
    sfa_kernel<<<4, 64, 0, stream>>>(tr, g_ws, out);
}